// Round 1
// 3208.686 us; speedup vs baseline: 1.0992x; 1.0992x over previous
//
#include <hip/hip_runtime.h>
#include <hip/hip_bf16.h>

typedef unsigned short u16;
typedef short bf16x8 __attribute__((ext_vector_type(8)));
typedef float floatx4 __attribute__((ext_vector_type(4)));
typedef u16 u16x4 __attribute__((ext_vector_type(4)));

#define DEV __device__ __forceinline__

DEV u16 f2bf(float f) {
    unsigned u = __builtin_bit_cast(unsigned, f);
    u += 0x7fffu + ((u >> 16) & 1u);
    return (u16)(u >> 16);
}
DEV float bf2f(u16 h) {
    unsigned u = ((unsigned)h) << 16;
    return __builtin_bit_cast(float, u);
}

static constexpr int Dm   = 768;
static constexpr int Hn   = 12;
static constexpr int HDn  = 64;
static constexpr int Ln   = 12;
static constexpr int Vn   = 50304;
static constexpr int Sn   = 1024;
static constexpr int Bn   = 2;
static constexpr int Tn   = Bn * Sn;     // 2048 tokens
static constexpr int DMLP = 4 * Dm;      // 3072

// global -> LDS async, 16B per lane, lane-linear LDS destination
#define GLOAD_LDS16(gptr, lptr)                                                        \
    __builtin_amdgcn_global_load_lds((const __attribute__((address_space(1))) void*)(gptr), \
                                     (__attribute__((address_space(3))) void*)(lptr), 16, 0, 0)

// ---------------------------------------------------------------------------
// fp32 -> bf16 flat convert (n4 = count/4, grid exact)
__global__ __launch_bounds__(256) void k_cvt(const float* __restrict__ s,
                                             u16* __restrict__ d, int n4) {
    int i = blockIdx.x * 256 + threadIdx.x;
    if (i >= n4) return;
    const float4 v = *(const float4*)(s + (size_t)i * 4);
    u16x4 o;
    o[0] = f2bf(v.x); o[1] = f2bf(v.y); o[2] = f2bf(v.z); o[3] = f2bf(v.w);
    *(u16x4*)(d + (size_t)i * 4) = o;
}

// transpose + convert: src [L][R][C] fp32 -> dst [L][C][R] bf16
__global__ __launch_bounds__(256) void k_tr(const float* __restrict__ src,
                                            u16* __restrict__ dst, int R, int C) {
    __shared__ float tile[32][33];
    const int l = blockIdx.z;
    src += (size_t)l * R * C;
    dst += (size_t)l * R * C;
    const int c0 = blockIdx.x * 32, r0 = blockIdx.y * 32;
    const int tx = threadIdx.x, ty = threadIdx.y; // 32 x 8
#pragma unroll
    for (int i = 0; i < 4; i++)
        tile[ty + i * 8][tx] = src[(size_t)(r0 + ty + i * 8) * C + c0 + tx];
    __syncthreads();
#pragma unroll
    for (int i = 0; i < 4; i++)
        dst[(size_t)(c0 + ty + i * 8) * R + r0 + tx] = f2bf(tile[tx][ty + i * 8]);
}

// embedding: x[t,d] = wte[ids[t],d] + wpe[t%S,d]
__global__ __launch_bounds__(256) void k_embed(const int* __restrict__ ids,
                                               const float* __restrict__ wte,
                                               const float* __restrict__ wpe,
                                               float* __restrict__ x) {
    int idx = blockIdx.x * 256 + threadIdx.x;      // < Tn*Dm
    int t = idx / Dm, d = idx - t * Dm;
    int s = t & (Sn - 1);
    x[idx] = wte[(size_t)ids[t] * Dm + d] + wpe[(size_t)s * Dm + d];
}

// layernorm over D=768, fp32 in -> bf16 out
__global__ __launch_bounds__(256) void k_ln(const float* __restrict__ x,
                                            const float* __restrict__ g,
                                            const float* __restrict__ bvec,
                                            u16* __restrict__ out, float eps) {
    const int row = blockIdx.x, tid = threadIdx.x;
    const float* xr = x + (size_t)row * Dm;
    float v0 = xr[tid], v1 = xr[tid + 256], v2 = xr[tid + 512];
    float s = v0 + v1 + v2;
    float q = v0 * v0 + v1 * v1 + v2 * v2;
#pragma unroll
    for (int off = 1; off < 64; off <<= 1) {
        s += __shfl_xor(s, off, 64);
        q += __shfl_xor(q, off, 64);
    }
    __shared__ float red[8];
    const int wid = tid >> 6;
    if ((tid & 63) == 0) { red[wid] = s; red[4 + wid] = q; }
    __syncthreads();
    s = red[0] + red[1] + red[2] + red[3];
    q = red[4] + red[5] + red[6] + red[7];
    const float mu  = s * (1.0f / Dm);
    const float var = q * (1.0f / Dm) - mu * mu;
    const float rs  = rsqrtf(var + eps);
    u16* orow = out + (size_t)row * Dm;
    orow[tid]       = f2bf((v0 - mu) * rs * g[tid]       + bvec[tid]);
    orow[tid + 256] = f2bf((v1 - mu) * rs * g[tid + 256] + bvec[tid + 256]);
    orow[tid + 512] = f2bf((v2 - mu) * rs * g[tid + 512] + bvec[tid + 512]);
}

// ---------------------------------------------------------------------------
// GEMM: C[M,N] = A[M,K] (bf16) @ W[N,K]^T (bf16) + bias
// MODE 0: fp32 out.
// MODE 2: bf16 out = gelu(acc+bias).
// MODE 3: fused qkv repack: bf16 scatter into q/k/v [B*H,S,64], q scaled 1/8.
// MODE 4: split-K over blockIdx.z, fp32 atomicAdd into outF (resid pre-loaded),
//         bias added by the z==0 split only.
// Grid: x = M/128 (fastest), y = N/128. Chunked XCD swizzle over (x,y);
// requires gridDim.x*gridDim.y % 8 == 0 (true for all launches below).
// 128x128 tile, BK=64, global_load_lds w/ XOR chunk swizzle, 16x16x32 bf16 MFMA.
template <int MODE>
__global__ __launch_bounds__(256) void k_gemm(const u16* __restrict__ A,
                                              const u16* __restrict__ W,
                                              const float* __restrict__ bias,
                                              float* __restrict__ outF,
                                              u16* __restrict__ outB,
                                              u16* __restrict__ outQ,
                                              u16* __restrict__ outK,
                                              u16* __restrict__ outV,
                                              int M, int N, int K) {
    __shared__ u16 sA[128 * 64];
    __shared__ u16 sW[128 * 64];
    const int tid = threadIdx.x;
    const int lane = tid & 63, wid = tid >> 6;
    const int lane16 = lane & 15, quad = lane >> 4;
    // m-fastest block order + chunked XCD swizzle: blocks sharing a W panel
    // run back-to-back on the same XCD -> W panel served from L2/L3 once.
    const int gx = gridDim.x;
    int bid = blockIdx.y * gx + blockIdx.x;
    bid = (bid & 7) * ((gx * gridDim.y) >> 3) + (bid >> 3);
    const int m0 = (bid % gx) * 128, n0 = (bid / gx) * 128;
    const int wm = wid & 1, wn = wid >> 1;

    floatx4 acc[4][4];
#pragma unroll
    for (int i = 0; i < 4; i++)
#pragma unroll
        for (int j = 0; j < 4; j++) acc[i][j] = (floatx4){0.f, 0.f, 0.f, 0.f};

    int kbeg = 0, kend = K;
    if (MODE == 4) {
        const int Kpart = K / (int)gridDim.z;
        kbeg = blockIdx.z * Kpart;
        kend = kbeg + Kpart;
    }

    for (int kb = kbeg; kb < kend; kb += 64) {
#pragma unroll
        for (int it = 0; it < 4; ++it) {
            int p = it * 256 + tid;           // LDS 16B-chunk slot, lane-linear
            int row = p >> 3;
            int kc = (p & 7) ^ (row & 7);     // fetch the chunk whose swizzled slot is p
            GLOAD_LDS16(A + (size_t)(m0 + row) * K + kb + kc * 8, sA + p * 8);
            GLOAD_LDS16(W + (size_t)(n0 + row) * K + kb + kc * 8, sW + p * 8);
        }
        __syncthreads();   // drains vmcnt(0) before barrier -> LDS ready
#pragma unroll
        for (int ks = 0; ks < 2; ++ks) {
            bf16x8 af[4], wf[4];
#pragma unroll
            for (int i = 0; i < 4; i++) {
                int m = wm * 64 + i * 16 + lane16;
                int ch = (ks * 4 + quad) ^ (m & 7);
                af[i] = *(const bf16x8*)(sA + m * 64 + ch * 8);
            }
#pragma unroll
            for (int j = 0; j < 4; j++) {
                int n = wn * 64 + j * 16 + lane16;
                int ch = (ks * 4 + quad) ^ (n & 7);
                wf[j] = *(const bf16x8*)(sW + n * 64 + ch * 8);
            }
#pragma unroll
            for (int i = 0; i < 4; i++)
#pragma unroll
                for (int j = 0; j < 4; j++)
                    acc[i][j] = __builtin_amdgcn_mfma_f32_16x16x32_bf16(af[i], wf[j], acc[i][j], 0, 0, 0);
        }
        __syncthreads();
    }

    // epilogue: D layout col = lane&15, row = quad*4 + r
#pragma unroll
    for (int i = 0; i < 4; i++) {
        int rowb = m0 + wm * 64 + i * 16 + quad * 4;
#pragma unroll
        for (int j = 0; j < 4; j++) {
            int col = n0 + wn * 64 + j * 16 + lane16;
            float bc = bias[col];
            if (MODE == 3) {
                // fused qkv split: col in [0,2304); h = col/192, which = (col%192)/64
                int h = col / 192, rem = col - h * 192;
                int which = rem >> 6, d = rem & 63;
                u16* dst = (which == 0) ? outQ : (which == 1) ? outK : outV;
                float scale = (which == 0) ? 0.125f : 1.0f;
#pragma unroll
                for (int r = 0; r < 4; r++) {
                    int t = rowb + r;
                    int b = t >> 10, s = t & (Sn - 1);
                    size_t o = ((size_t)(b * Hn + h) * Sn + s) * HDn + d;
                    dst[o] = f2bf((acc[i][j][r] + bc) * scale);
                }
            } else {
#pragma unroll
                for (int r = 0; r < 4; r++) {
                    size_t off = (size_t)(rowb + r) * N + col;
                    if (MODE == 0) {
                        outF[off] = acc[i][j][r] + bc;
                    } else if (MODE == 2) {
                        float v = acc[i][j][r] + bc;
                        float gl = 0.5f * v * (1.0f + erff(v * 0.70710678118654752f));
                        outB[off] = f2bf(gl);
                    } else { // MODE 4
                        float v = acc[i][j][r];
                        if (blockIdx.z == 0) v += bc;
                        atomicAdd(outF + off, v);
                    }
                }
            }
        }
    }
}

// ---------------------------------------------------------------------------
// flash attention: Q,K,V bf16 [B*H, S, 64] (Q pre-scaled 1/8), out bf16 [T, 768]
// block = 4 waves, 64-query tile; wave w owns query rows w*16..w*16+15
__global__ __launch_bounds__(256) void k_attn(const u16* __restrict__ Q,
                                              const u16* __restrict__ Kg,
                                              const u16* __restrict__ Vg,
                                              const float* __restrict__ amask,
                                              u16* __restrict__ out) {
    __shared__ u16 sQ[64 * 72];
    __shared__ u16 sK[64 * 72];
    __shared__ u16 sV[64 * 72];   // transposed: [dim][key]
    __shared__ u16 sP[64 * 72];
    const int tid = threadIdx.x;
    const int lane = tid & 63, wid = tid >> 6;
    const int lane16 = lane & 15, quad = lane >> 4;
    const int blk = blockIdx.x;
    const int qt = blk & 15, bh = blk >> 4;
    const int b = bh / Hn, h = bh - b * Hn;
    const int q0 = qt * 64;
    const u16* Qb = Q + (size_t)bh * Sn * HDn;
    const u16* Kb = Kg + (size_t)bh * Sn * HDn;
    const u16* Vb = Vg + (size_t)bh * Sn * HDn;
    const float* maskb = amask + (size_t)b * Sn;

    // stage Q tile [64][72]
#pragma unroll
    for (int it = 0; it < 2; ++it) {
        int c = it * 256 + tid;
        int row = c >> 3, kc = c & 7;
        *(bf16x8*)(sQ + row * 72 + kc * 8) = *(const bf16x8*)(Qb + (size_t)(q0 + row) * HDn + kc * 8);
    }

    float mrow[4], lrow[4];
    floatx4 o[4];
#pragma unroll
    for (int r = 0; r < 4; r++) { mrow[r] = -1e30f; lrow[r] = 0.f; }
#pragma unroll
    for (int t = 0; t < 4; t++) o[t] = (floatx4){0.f, 0.f, 0.f, 0.f};

    for (int kt = 0; kt <= qt; ++kt) {
        __syncthreads();   // prev-iter reads done (also makes Q visible on iter 0)
        const int k0 = kt * 64;
#pragma unroll
        for (int it = 0; it < 2; ++it) {
            int c = it * 256 + tid;
            int row = c >> 3, kc = c & 7;
            bf16x8 kv = *(const bf16x8*)(Kb + (size_t)(k0 + row) * HDn + kc * 8);
            *(bf16x8*)(sK + row * 72 + kc * 8) = kv;
            bf16x8 vv = *(const bf16x8*)(Vb + (size_t)(k0 + row) * HDn + kc * 8);
#pragma unroll
            for (int u = 0; u < 8; u++) sV[(kc * 8 + u) * 72 + row] = (u16)vv[u];
        }
        __syncthreads();

        // S = Q K^T  (Q already carries 1/sqrt(64))
        floatx4 s[4];
#pragma unroll
        for (int t = 0; t < 4; t++) s[t] = (floatx4){0.f, 0.f, 0.f, 0.f};
#pragma unroll
        for (int ks = 0; ks < 2; ++ks) {
            bf16x8 aq = *(const bf16x8*)(sQ + (wid * 16 + lane16) * 72 + ks * 32 + quad * 8);
#pragma unroll
            for (int t = 0; t < 4; t++) {
                bf16x8 bk = *(const bf16x8*)(sK + (t * 16 + lane16) * 72 + ks * 32 + quad * 8);
                s[t] = __builtin_amdgcn_mfma_f32_16x16x32_bf16(aq, bk, s[t], 0, 0, 0);
            }
        }

        // mask: causal -> -10000, then + mask_add (matches reference order)
        float madd[4];
#pragma unroll
        for (int t = 0; t < 4; t++)
            madd[t] = (1.0f - maskb[k0 + t * 16 + lane16]) * -10000.0f;
#pragma unroll
        for (int t = 0; t < 4; t++) {
            int kg = k0 + t * 16 + lane16;
#pragma unroll
            for (int r = 0; r < 4; r++) {
                int qg = q0 + wid * 16 + quad * 4 + r;
                float val = s[t][r];
                if (kg > qg) val = -10000.0f;
                s[t][r] = val + madd[t];
            }
        }

        // online softmax (row state per lane-reg; rows of this quad)
        float mnew[4], alpha[4], rsum[4];
#pragma unroll
        for (int r = 0; r < 4; r++) {
            float mx = fmaxf(fmaxf(s[0][r], s[1][r]), fmaxf(s[2][r], s[3][r]));
#pragma unroll
            for (int off = 1; off < 16; off <<= 1) mx = fmaxf(mx, __shfl_xor(mx, off, 64));
            mnew[r] = fmaxf(mrow[r], mx);
            alpha[r] = expf(mrow[r] - mnew[r]);
            rsum[r] = 0.f;
        }
#pragma unroll
        for (int t = 0; t < 4; t++) {
#pragma unroll
            for (int r = 0; r < 4; r++) {
                float p = expf(s[t][r] - mnew[r]);
                rsum[r] += p;
                sP[(wid * 16 + quad * 4 + r) * 72 + t * 16 + lane16] = f2bf(p);
            }
        }
#pragma unroll
        for (int r = 0; r < 4; r++) {
#pragma unroll
            for (int off = 1; off < 16; off <<= 1) rsum[r] += __shfl_xor(rsum[r], off, 64);
            lrow[r] = lrow[r] * alpha[r] + rsum[r];
            mrow[r] = mnew[r];
        }
#pragma unroll
        for (int t = 0; t < 4; t++)
#pragma unroll
            for (int r = 0; r < 4; r++) o[t][r] *= alpha[r];

        __builtin_amdgcn_wave_barrier();   // keep P writes before P reads (same wave, in-order DS)

        // O += P @ V
#pragma unroll
        for (int ks = 0; ks < 2; ++ks) {
            bf16x8 ap = *(const bf16x8*)(sP + (wid * 16 + lane16) * 72 + ks * 32 + quad * 8);
#pragma unroll
            for (int t = 0; t < 4; t++) {
                bf16x8 bv = *(const bf16x8*)(sV + (t * 16 + lane16) * 72 + ks * 32 + quad * 8);
                o[t] = __builtin_amdgcn_mfma_f32_16x16x32_bf16(ap, bv, o[t], 0, 0, 0);
            }
        }
    }

    // write O/l to attn_out [T, 768] at column h*64+dim
#pragma unroll
    for (int t = 0; t < 4; t++) {
#pragma unroll
        for (int r = 0; r < 4; r++) {
            int qg = q0 + wid * 16 + quad * 4 + r;
            float val = o[t][r] / lrow[r];
            out[(size_t)(b * Sn + qg) * Dm + h * HDn + t * 16 + lane16] = f2bf(val);
        }
    }
}

// ---------------------------------------------------------------------------
extern "C" void kernel_launch(void* const* d_in, const int* in_sizes, int n_in,
                              void* d_out, int out_size, void* d_ws, size_t ws_size,
                              hipStream_t stream) {
    (void)in_sizes; (void)n_in; (void)out_size; (void)ws_size;

    const int*   ids   = (const int*)  d_in[0];
    const float* amask = (const float*)d_in[1];
    const float* wte   = (const float*)d_in[2];
    const float* wpe   = (const float*)d_in[3];
    const float* ln1g  = (const float*)d_in[4];
    const float* ln1b  = (const float*)d_in[5];
    const float* qkvw  = (const float*)d_in[6];
    const float* qkvb  = (const float*)d_in[7];
    const float* projw = (const float*)d_in[8];
    const float* projb = (const float*)d_in[9];
    const float* ln2g  = (const float*)d_in[10];
    const float* ln2b  = (const float*)d_in[11];
    const float* fc1w  = (const float*)d_in[12];
    const float* fc1b  = (const float*)d_in[13];
    const float* fc2w  = (const float*)d_in[14];
    const float* fc2b  = (const float*)d_in[15];
    const float* lnfg  = (const float*)d_in[16];
    const float* lnfb  = (const float*)d_in[17];
    const float* headb = (const float*)d_in[18];

    char* w = (char*)d_ws;
    u16* wteB = (u16*)w;   w += (size_t)Vn * Dm * 2;
    u16* qkvW = (u16*)w;   w += (size_t)Ln * Dm * 3 * Dm * 2;
    u16* projW = (u16*)w;  w += (size_t)Ln * Dm * Dm * 2;
    u16* fc1W = (u16*)w;   w += (size_t)Ln * Dm * DMLP * 2;
    u16* fc2W = (u16*)w;   w += (size_t)Ln * DMLP * Dm * 2;
    float* x  = (float*)w; w += (size_t)Tn * Dm * 4;
    u16* hbuf = (u16*)w;   w += (size_t)Tn * Dm * 2;
    u16* qb   = (u16*)w;   w += (size_t)Tn * Dm * 2;
    u16* kb   = (u16*)w;   w += (size_t)Tn * Dm * 2;
    u16* vb   = (u16*)w;   w += (size_t)Tn * Dm * 2;
    u16* attn = (u16*)w;   w += (size_t)Tn * Dm * 2;
    u16* mlp  = (u16*)w;   w += (size_t)Tn * DMLP * 2;

    // ---- weight prep (bf16 + transpose to [N,K]) ----
    k_cvt<<<(Vn * Dm / 4) / 256, 256, 0, stream>>>(wte, wteB, Vn * Dm / 4);
    dim3 tb(32, 8);
    k_tr<<<dim3(3 * Dm / 32, Dm / 32, Ln), tb, 0, stream>>>(qkvw, qkvW, Dm, 3 * Dm);
    k_tr<<<dim3(Dm / 32, Dm / 32, Ln), tb, 0, stream>>>(projw, projW, Dm, Dm);
    k_tr<<<dim3(DMLP / 32, Dm / 32, Ln), tb, 0, stream>>>(fc1w, fc1W, Dm, DMLP);
    k_tr<<<dim3(Dm / 32, DMLP / 32, Ln), tb, 0, stream>>>(fc2w, fc2W, DMLP, Dm);

    k_embed<<<Tn * Dm / 256, 256, 0, stream>>>(ids, wte, wpe, x);

    for (int l = 0; l < Ln; ++l) {
        k_ln<<<Tn, 256, 0, stream>>>(x, ln1g + l * Dm, ln1b + l * Dm, hbuf, 1e-6f);
        // qkv GEMM with fused repack into q/k/v (q pre-scaled 1/8)
        k_gemm<3><<<dim3(Tn / 128, 3 * Dm / 128), 256, 0, stream>>>(
            hbuf, qkvW + (size_t)l * 3 * Dm * Dm, qkvb + l * 3 * Dm,
            nullptr, nullptr, qb, kb, vb, Tn, 3 * Dm, Dm);
        k_attn<<<Bn * Hn * (Sn / 64), 256, 0, stream>>>(qb, kb, vb, amask, attn);
        // proj: split-K=4, atomic accumulate into x (x already holds residual)
        k_gemm<4><<<dim3(Tn / 128, Dm / 128, 4), 256, 0, stream>>>(
            attn, projW + (size_t)l * Dm * Dm, projb + l * Dm,
            x, nullptr, nullptr, nullptr, nullptr, Tn, Dm, Dm);
        k_ln<<<Tn, 256, 0, stream>>>(x, ln2g + l * Dm, ln2b + l * Dm, hbuf, 1e-6f);
        k_gemm<2><<<dim3(Tn / 128, DMLP / 128), 256, 0, stream>>>(
            hbuf, fc1W + (size_t)l * Dm * DMLP, fc1b + l * DMLP,
            nullptr, mlp, nullptr, nullptr, nullptr, Tn, DMLP, Dm);
        // fc2: split-K=4, atomic accumulate into x
        k_gemm<4><<<dim3(Tn / 128, Dm / 128, 4), 256, 0, stream>>>(
            mlp, fc2W + (size_t)l * DMLP * Dm, fc2b + l * Dm,
            x, nullptr, nullptr, nullptr, nullptr, Tn, Dm, DMLP);
    }

    k_ln<<<Tn, 256, 0, stream>>>(x, lnfg, lnfb, hbuf, 1e-5f);
    k_gemm<0><<<dim3(Tn / 128, Vn / 128), 256, 0, stream>>>(
        hbuf, wteB, headb, (float*)d_out, nullptr, nullptr, nullptr, nullptr,
        Tn, Vn, Dm);
}

// Round 2
// 3125.793 us; speedup vs baseline: 1.1283x; 1.0265x over previous
//
#include <hip/hip_runtime.h>
#include <hip/hip_bf16.h>

typedef unsigned short u16;
typedef short bf16x8 __attribute__((ext_vector_type(8)));
typedef float floatx4 __attribute__((ext_vector_type(4)));
typedef u16 u16x4 __attribute__((ext_vector_type(4)));

#define DEV __device__ __forceinline__

DEV u16 f2bf(float f) {
    unsigned u = __builtin_bit_cast(unsigned, f);
    u += 0x7fffu + ((u >> 16) & 1u);
    return (u16)(u >> 16);
}
DEV float bf2f(u16 h) {
    unsigned u = ((unsigned)h) << 16;
    return __builtin_bit_cast(float, u);
}

static constexpr int Dm   = 768;
static constexpr int Hn   = 12;
static constexpr int HDn  = 64;
static constexpr int Ln   = 12;
static constexpr int Vn   = 50304;
static constexpr int Sn   = 1024;
static constexpr int Bn   = 2;
static constexpr int Tn   = Bn * Sn;     // 2048 tokens
static constexpr int DMLP = 4 * Dm;      // 3072

// global -> LDS async, 16B per lane, lane-linear LDS destination
#define GLOAD_LDS16(gptr, lptr)                                                        \
    __builtin_amdgcn_global_load_lds((const __attribute__((address_space(1))) void*)(gptr), \
                                     (__attribute__((address_space(3))) void*)(lptr), 16, 0, 0)

// ---------------------------------------------------------------------------
// fp32 -> bf16 flat convert (n4 = count/4, grid exact)
__global__ __launch_bounds__(256) void k_cvt(const float* __restrict__ s,
                                             u16* __restrict__ d, int n4) {
    int i = blockIdx.x * 256 + threadIdx.x;
    if (i >= n4) return;
    const float4 v = *(const float4*)(s + (size_t)i * 4);
    u16x4 o;
    o[0] = f2bf(v.x); o[1] = f2bf(v.y); o[2] = f2bf(v.z); o[3] = f2bf(v.w);
    *(u16x4*)(d + (size_t)i * 4) = o;
}

// transpose + convert: src [L][R][C] fp32 -> dst [L][C][R] bf16
__global__ __launch_bounds__(256) void k_tr(const float* __restrict__ src,
                                            u16* __restrict__ dst, int R, int C) {
    __shared__ float tile[32][33];
    const int l = blockIdx.z;
    src += (size_t)l * R * C;
    dst += (size_t)l * R * C;
    const int c0 = blockIdx.x * 32, r0 = blockIdx.y * 32;
    const int tx = threadIdx.x, ty = threadIdx.y; // 32 x 8
#pragma unroll
    for (int i = 0; i < 4; i++)
        tile[ty + i * 8][tx] = src[(size_t)(r0 + ty + i * 8) * C + c0 + tx];
    __syncthreads();
#pragma unroll
    for (int i = 0; i < 4; i++)
        dst[(size_t)(c0 + ty + i * 8) * R + r0 + tx] = f2bf(tile[tx][ty + i * 8]);
}

// embedding: x[t,d] = wte[ids[t],d] + wpe[t%S,d]
__global__ __launch_bounds__(256) void k_embed(const int* __restrict__ ids,
                                               const float* __restrict__ wte,
                                               const float* __restrict__ wpe,
                                               float* __restrict__ x) {
    int idx = blockIdx.x * 256 + threadIdx.x;      // < Tn*Dm
    int t = idx / Dm, d = idx - t * Dm;
    int s = t & (Sn - 1);
    x[idx] = wte[(size_t)ids[t] * Dm + d] + wpe[(size_t)s * Dm + d];
}

// layernorm over D=768, fp32 in -> bf16 out
__global__ __launch_bounds__(256) void k_ln(const float* __restrict__ x,
                                            const float* __restrict__ g,
                                            const float* __restrict__ bvec,
                                            u16* __restrict__ out, float eps) {
    const int row = blockIdx.x, tid = threadIdx.x;
    const float* xr = x + (size_t)row * Dm;
    float v0 = xr[tid], v1 = xr[tid + 256], v2 = xr[tid + 512];
    float s = v0 + v1 + v2;
    float q = v0 * v0 + v1 * v1 + v2 * v2;
#pragma unroll
    for (int off = 1; off < 64; off <<= 1) {
        s += __shfl_xor(s, off, 64);
        q += __shfl_xor(q, off, 64);
    }
    __shared__ float red[8];
    const int wid = tid >> 6;
    if ((tid & 63) == 0) { red[wid] = s; red[4 + wid] = q; }
    __syncthreads();
    s = red[0] + red[1] + red[2] + red[3];
    q = red[4] + red[5] + red[6] + red[7];
    const float mu  = s * (1.0f / Dm);
    const float var = q * (1.0f / Dm) - mu * mu;
    const float rs  = rsqrtf(var + eps);
    u16* orow = out + (size_t)row * Dm;
    orow[tid]       = f2bf((v0 - mu) * rs * g[tid]       + bvec[tid]);
    orow[tid + 256] = f2bf((v1 - mu) * rs * g[tid + 256] + bvec[tid + 256]);
    orow[tid + 512] = f2bf((v2 - mu) * rs * g[tid + 512] + bvec[tid + 512]);
}

// ---------------------------------------------------------------------------
// GEMM: C[M,N] = A[M,K] (bf16) @ W[N,K]^T (bf16) + bias
// MODE 0: fp32 out.
// MODE 2: bf16 out = gelu(acc+bias).
// MODE 3: fused qkv repack: bf16 scatter into q/k/v [B*H,S,64], q scaled 1/8.
// MODE 4: split-K over blockIdx.z, fp32 atomicAdd into outF (resid pre-loaded),
//         bias added by the z==0 split only.
// Grid: x = M/128 (fastest), y = N/128. Chunked XCD swizzle over (x,y);
// requires gridDim.x*gridDim.y % 8 == 0 (true for all launches below).
// 128x128 tile, BK=64, global_load_lds w/ XOR chunk swizzle, 16x16x32 bf16 MFMA.
template <int MODE>
__global__ __launch_bounds__(256) void k_gemm(const u16* __restrict__ A,
                                              const u16* __restrict__ W,
                                              const float* __restrict__ bias,
                                              float* __restrict__ outF,
                                              u16* __restrict__ outB,
                                              u16* __restrict__ outQ,
                                              u16* __restrict__ outK,
                                              u16* __restrict__ outV,
                                              int M, int N, int K) {
    __shared__ u16 sA[128 * 64];
    __shared__ u16 sW[128 * 64];
    const int tid = threadIdx.x;
    const int lane = tid & 63, wid = tid >> 6;
    const int lane16 = lane & 15, quad = lane >> 4;
    const int gx = gridDim.x;
    int bid = blockIdx.y * gx + blockIdx.x;
    bid = (bid & 7) * ((gx * gridDim.y) >> 3) + (bid >> 3);
    const int m0 = (bid % gx) * 128, n0 = (bid / gx) * 128;
    const int wm = wid & 1, wn = wid >> 1;

    floatx4 acc[4][4];
#pragma unroll
    for (int i = 0; i < 4; i++)
#pragma unroll
        for (int j = 0; j < 4; j++) acc[i][j] = (floatx4){0.f, 0.f, 0.f, 0.f};

    int kbeg = 0, kend = K;
    if (MODE == 4) {
        const int Kpart = K / (int)gridDim.z;
        kbeg = blockIdx.z * Kpart;
        kend = kbeg + Kpart;
    }

    for (int kb = kbeg; kb < kend; kb += 64) {
#pragma unroll
        for (int it = 0; it < 4; ++it) {
            int p = it * 256 + tid;           // LDS 16B-chunk slot, lane-linear
            int row = p >> 3;
            int kc = (p & 7) ^ (row & 7);     // fetch the chunk whose swizzled slot is p
            GLOAD_LDS16(A + (size_t)(m0 + row) * K + kb + kc * 8, sA + p * 8);
            GLOAD_LDS16(W + (size_t)(n0 + row) * K + kb + kc * 8, sW + p * 8);
        }
        __syncthreads();   // drains vmcnt(0) before barrier -> LDS ready
#pragma unroll
        for (int ks = 0; ks < 2; ++ks) {
            bf16x8 af[4], wf[4];
#pragma unroll
            for (int i = 0; i < 4; i++) {
                int m = wm * 64 + i * 16 + lane16;
                int ch = (ks * 4 + quad) ^ (m & 7);
                af[i] = *(const bf16x8*)(sA + m * 64 + ch * 8);
            }
#pragma unroll
            for (int j = 0; j < 4; j++) {
                int n = wn * 64 + j * 16 + lane16;
                int ch = (ks * 4 + quad) ^ (n & 7);
                wf[j] = *(const bf16x8*)(sW + n * 64 + ch * 8);
            }
#pragma unroll
            for (int i = 0; i < 4; i++)
#pragma unroll
                for (int j = 0; j < 4; j++)
                    acc[i][j] = __builtin_amdgcn_mfma_f32_16x16x32_bf16(af[i], wf[j], acc[i][j], 0, 0, 0);
        }
        __syncthreads();
    }

    // epilogue: D layout col = lane&15, row = quad*4 + r
#pragma unroll
    for (int i = 0; i < 4; i++) {
        int rowb = m0 + wm * 64 + i * 16 + quad * 4;
#pragma unroll
        for (int j = 0; j < 4; j++) {
            int col = n0 + wn * 64 + j * 16 + lane16;
            float bc = bias[col];
            if (MODE == 3) {
                int h = col / 192, rem = col - h * 192;
                int which = rem >> 6, d = rem & 63;
                u16* dst = (which == 0) ? outQ : (which == 1) ? outK : outV;
                float scale = (which == 0) ? 0.125f : 1.0f;
#pragma unroll
                for (int r = 0; r < 4; r++) {
                    int t = rowb + r;
                    int b = t >> 10, s = t & (Sn - 1);
                    size_t o = ((size_t)(b * Hn + h) * Sn + s) * HDn + d;
                    dst[o] = f2bf((acc[i][j][r] + bc) * scale);
                }
            } else {
#pragma unroll
                for (int r = 0; r < 4; r++) {
                    size_t off = (size_t)(rowb + r) * N + col;
                    if (MODE == 0) {
                        outF[off] = acc[i][j][r] + bc;
                    } else if (MODE == 2) {
                        float v = acc[i][j][r] + bc;
                        float gl = 0.5f * v * (1.0f + erff(v * 0.70710678118654752f));
                        outB[off] = f2bf(gl);
                    } else { // MODE 4
                        float v = acc[i][j][r];
                        if (blockIdx.z == 0) v += bc;
                        atomicAdd(outF + off, v);
                    }
                }
            }
        }
    }
}

// ---------------------------------------------------------------------------
// Head GEMM: 256x128 tile, BK=64, 8 waves (512 thr), double-buffered LDS,
// counted vmcnt(6) + raw barriers (no vmcnt(0) drain in the main loop).
// Requires M % 256 == 0, N % 128 == 0, K % 64 == 0, K >= 128, grid % 8 == 0.
DEV void hstage(const u16* __restrict__ A, const u16* __restrict__ W, int K,
                int m0, int n0, int kb, u16* sA, u16* sB, int tid) {
#pragma unroll
    for (int it = 0; it < 4; ++it) {
        int p = it * 512 + tid;            // A: 256 rows x 8 chunks
        int row = p >> 3;
        int kc = (p & 7) ^ (row & 7);
        GLOAD_LDS16(A + (size_t)(m0 + row) * K + kb + kc * 8, sA + p * 8);
    }
#pragma unroll
    for (int it = 0; it < 2; ++it) {
        int p = it * 512 + tid;            // B: 128 rows x 8 chunks
        int row = p >> 3;
        int kc = (p & 7) ^ (row & 7);
        GLOAD_LDS16(W + (size_t)(n0 + row) * K + kb + kc * 8, sB + p * 8);
    }
}

__global__ __launch_bounds__(512, 2) void k_hgemm(const u16* __restrict__ A,
                                                  const u16* __restrict__ W,
                                                  const float* __restrict__ bias,
                                                  float* __restrict__ outF,
                                                  int M, int N, int K) {
    __shared__ u16 sA[2][256 * 64];
    __shared__ u16 sB[2][128 * 64];
    const int tid = threadIdx.x;
    const int lane = tid & 63, wid = tid >> 6;
    const int lane16 = lane & 15, quad = lane >> 4;
    const int gxM = M >> 8;                       // m-tiles (8)
    int b = blockIdx.x;
    int nb = (b & 7) * ((int)gridDim.x >> 3) + (b >> 3);   // XCD chunk swizzle
    const int m0 = (nb % gxM) * 256;              // m fastest
    const int n0 = (nb / gxM) * 128;
    const int wm = wid & 3, wn = wid >> 2;        // 4 x 2 wave grid

    floatx4 acc[4][4];
#pragma unroll
    for (int i = 0; i < 4; i++)
#pragma unroll
        for (int j = 0; j < 4; j++) acc[i][j] = (floatx4){0.f, 0.f, 0.f, 0.f};

    const int KT = K >> 6;
    hstage(A, W, K, m0, n0, 0, sA[0], sB[0], tid);
    hstage(A, W, K, m0, n0, 64, sA[1], sB[1], tid);

    for (int kt = 0; kt < KT; ++kt) {
        const int p = kt & 1;
        // wait this tile's 6 loads only; next tile's 6 stay in flight
        if (kt + 1 < KT) asm volatile("s_waitcnt vmcnt(6)" ::: "memory");
        else             asm volatile("s_waitcnt vmcnt(0)" ::: "memory");
        __builtin_amdgcn_s_barrier();

        bf16x8 af[2][4], wf[2][4];
#pragma unroll
        for (int ks = 0; ks < 2; ++ks) {
#pragma unroll
            for (int i = 0; i < 4; i++) {
                int m = wm * 64 + i * 16 + lane16;
                int ch = (ks * 4 + quad) ^ (m & 7);
                af[ks][i] = *(const bf16x8*)(sA[p] + m * 64 + ch * 8);
            }
#pragma unroll
            for (int j = 0; j < 4; j++) {
                int n = wn * 64 + j * 16 + lane16;
                int ch = (ks * 4 + quad) ^ (n & 7);
                wf[ks][j] = *(const bf16x8*)(sB[p] + n * 64 + ch * 8);
            }
        }
        // reads must complete before any wave overwrites this buffer
        asm volatile("s_waitcnt lgkmcnt(0)" ::: "memory");
        __builtin_amdgcn_sched_barrier(0);
        __builtin_amdgcn_s_barrier();

        if (kt + 2 < KT)
            hstage(A, W, K, m0, n0, (kt + 2) << 6, sA[p], sB[p], tid);

        __builtin_amdgcn_s_setprio(1);
#pragma unroll
        for (int ks = 0; ks < 2; ++ks)
#pragma unroll
            for (int i = 0; i < 4; i++)
#pragma unroll
                for (int j = 0; j < 4; j++)
                    acc[i][j] = __builtin_amdgcn_mfma_f32_16x16x32_bf16(af[ks][i], wf[ks][j], acc[i][j], 0, 0, 0);
        __builtin_amdgcn_s_setprio(0);
    }

    // epilogue: D layout col = lane&15, row = quad*4 + r
#pragma unroll
    for (int i = 0; i < 4; i++) {
        int rowb = m0 + wm * 64 + i * 16 + quad * 4;
#pragma unroll
        for (int j = 0; j < 4; j++) {
            int col = n0 + wn * 64 + j * 16 + lane16;
            float bc = bias[col];
#pragma unroll
            for (int r = 0; r < 4; r++) {
                size_t off = (size_t)(rowb + r) * N + col;
                outF[off] = acc[i][j][r] + bc;
            }
        }
    }
}

// ---------------------------------------------------------------------------
// flash attention: Q,K,V bf16 [B*H, S, 64] (Q pre-scaled 1/8), out bf16 [T, 768]
// block = 4 waves, 64-query tile; wave w owns query rows w*16..w*16+15
__global__ __launch_bounds__(256) void k_attn(const u16* __restrict__ Q,
                                              const u16* __restrict__ Kg,
                                              const u16* __restrict__ Vg,
                                              const float* __restrict__ amask,
                                              u16* __restrict__ out) {
    __shared__ u16 sQ[64 * 72];
    __shared__ u16 sK[64 * 72];
    __shared__ u16 sV[64 * 72];   // transposed: [dim][key]
    __shared__ u16 sP[64 * 72];
    const int tid = threadIdx.x;
    const int lane = tid & 63, wid = tid >> 6;
    const int lane16 = lane & 15, quad = lane >> 4;
    const int blk = blockIdx.x;
    const int qt = blk & 15, bh = blk >> 4;
    const int b = bh / Hn, h = bh - b * Hn;
    const int q0 = qt * 64;
    const u16* Qb = Q + (size_t)bh * Sn * HDn;
    const u16* Kb = Kg + (size_t)bh * Sn * HDn;
    const u16* Vb = Vg + (size_t)bh * Sn * HDn;
    const float* maskb = amask + (size_t)b * Sn;

    // stage Q tile [64][72]
#pragma unroll
    for (int it = 0; it < 2; ++it) {
        int c = it * 256 + tid;
        int row = c >> 3, kc = c & 7;
        *(bf16x8*)(sQ + row * 72 + kc * 8) = *(const bf16x8*)(Qb + (size_t)(q0 + row) * HDn + kc * 8);
    }

    float mrow[4], lrow[4];
    floatx4 o[4];
#pragma unroll
    for (int r = 0; r < 4; r++) { mrow[r] = -1e30f; lrow[r] = 0.f; }
#pragma unroll
    for (int t = 0; t < 4; t++) o[t] = (floatx4){0.f, 0.f, 0.f, 0.f};

    for (int kt = 0; kt <= qt; ++kt) {
        __syncthreads();   // prev-iter reads done (also makes Q visible on iter 0)
        const int k0 = kt * 64;
#pragma unroll
        for (int it = 0; it < 2; ++it) {
            int c = it * 256 + tid;
            int row = c >> 3, kc = c & 7;
            bf16x8 kv = *(const bf16x8*)(Kb + (size_t)(k0 + row) * HDn + kc * 8);
            *(bf16x8*)(sK + row * 72 + kc * 8) = kv;
            bf16x8 vv = *(const bf16x8*)(Vb + (size_t)(k0 + row) * HDn + kc * 8);
#pragma unroll
            for (int u = 0; u < 8; u++) sV[(kc * 8 + u) * 72 + row] = (u16)vv[u];
        }
        __syncthreads();

        // S = Q K^T  (Q already carries 1/sqrt(64))
        floatx4 s[4];
#pragma unroll
        for (int t = 0; t < 4; t++) s[t] = (floatx4){0.f, 0.f, 0.f, 0.f};
        __builtin_amdgcn_s_setprio(1);
#pragma unroll
        for (int ks = 0; ks < 2; ++ks) {
            bf16x8 aq = *(const bf16x8*)(sQ + (wid * 16 + lane16) * 72 + ks * 32 + quad * 8);
#pragma unroll
            for (int t = 0; t < 4; t++) {
                bf16x8 bk = *(const bf16x8*)(sK + (t * 16 + lane16) * 72 + ks * 32 + quad * 8);
                s[t] = __builtin_amdgcn_mfma_f32_16x16x32_bf16(aq, bk, s[t], 0, 0, 0);
            }
        }
        __builtin_amdgcn_s_setprio(0);

        // mask: causal -> -10000, then + mask_add (matches reference order)
        float madd[4];
#pragma unroll
        for (int t = 0; t < 4; t++)
            madd[t] = (1.0f - maskb[k0 + t * 16 + lane16]) * -10000.0f;
#pragma unroll
        for (int t = 0; t < 4; t++) {
            int kg = k0 + t * 16 + lane16;
#pragma unroll
            for (int r = 0; r < 4; r++) {
                int qg = q0 + wid * 16 + quad * 4 + r;
                float val = s[t][r];
                if (kg > qg) val = -10000.0f;
                s[t][r] = val + madd[t];
            }
        }

        // online softmax (row state per lane-reg; rows of this quad)
        float mnew[4], alpha[4], rsum[4];
#pragma unroll
        for (int r = 0; r < 4; r++) {
            float mx = fmaxf(fmaxf(s[0][r], s[1][r]), fmaxf(s[2][r], s[3][r]));
#pragma unroll
            for (int off = 1; off < 16; off <<= 1) mx = fmaxf(mx, __shfl_xor(mx, off, 64));
            mnew[r] = fmaxf(mrow[r], mx);
            alpha[r] = expf(mrow[r] - mnew[r]);
            rsum[r] = 0.f;
        }
#pragma unroll
        for (int t = 0; t < 4; t++) {
#pragma unroll
            for (int r = 0; r < 4; r++) {
                float p = expf(s[t][r] - mnew[r]);
                rsum[r] += p;
                sP[(wid * 16 + quad * 4 + r) * 72 + t * 16 + lane16] = f2bf(p);
            }
        }
#pragma unroll
        for (int r = 0; r < 4; r++) {
#pragma unroll
            for (int off = 1; off < 16; off <<= 1) rsum[r] += __shfl_xor(rsum[r], off, 64);
            lrow[r] = lrow[r] * alpha[r] + rsum[r];
            mrow[r] = mnew[r];
        }
#pragma unroll
        for (int t = 0; t < 4; t++)
#pragma unroll
            for (int r = 0; r < 4; r++) o[t][r] *= alpha[r];

        __builtin_amdgcn_wave_barrier();   // keep P writes before P reads (same wave, in-order DS)

        // O += P @ V
        __builtin_amdgcn_s_setprio(1);
#pragma unroll
        for (int ks = 0; ks < 2; ++ks) {
            bf16x8 ap = *(const bf16x8*)(sP + (wid * 16 + lane16) * 72 + ks * 32 + quad * 8);
#pragma unroll
            for (int t = 0; t < 4; t++) {
                bf16x8 bv = *(const bf16x8*)(sV + (t * 16 + lane16) * 72 + ks * 32 + quad * 8);
                o[t] = __builtin_amdgcn_mfma_f32_16x16x32_bf16(ap, bv, o[t], 0, 0, 0);
            }
        }
        __builtin_amdgcn_s_setprio(0);
    }

    // write O/l to attn_out [T, 768] at column h*64+dim
#pragma unroll
    for (int t = 0; t < 4; t++) {
#pragma unroll
        for (int r = 0; r < 4; r++) {
            int qg = q0 + wid * 16 + quad * 4 + r;
            float val = o[t][r] / lrow[r];
            out[(size_t)(b * Sn + qg) * Dm + h * HDn + t * 16 + lane16] = f2bf(val);
        }
    }
}

// ---------------------------------------------------------------------------
extern "C" void kernel_launch(void* const* d_in, const int* in_sizes, int n_in,
                              void* d_out, int out_size, void* d_ws, size_t ws_size,
                              hipStream_t stream) {
    (void)in_sizes; (void)n_in; (void)out_size; (void)ws_size;

    const int*   ids   = (const int*)  d_in[0];
    const float* amask = (const float*)d_in[1];
    const float* wte   = (const float*)d_in[2];
    const float* wpe   = (const float*)d_in[3];
    const float* ln1g  = (const float*)d_in[4];
    const float* ln1b  = (const float*)d_in[5];
    const float* qkvw  = (const float*)d_in[6];
    const float* qkvb  = (const float*)d_in[7];
    const float* projw = (const float*)d_in[8];
    const float* projb = (const float*)d_in[9];
    const float* ln2g  = (const float*)d_in[10];
    const float* ln2b  = (const float*)d_in[11];
    const float* fc1w  = (const float*)d_in[12];
    const float* fc1b  = (const float*)d_in[13];
    const float* fc2w  = (const float*)d_in[14];
    const float* fc2b  = (const float*)d_in[15];
    const float* lnfg  = (const float*)d_in[16];
    const float* lnfb  = (const float*)d_in[17];
    const float* headb = (const float*)d_in[18];

    char* w = (char*)d_ws;
    u16* wteB = (u16*)w;   w += (size_t)Vn * Dm * 2;
    u16* qkvW = (u16*)w;   w += (size_t)Ln * Dm * 3 * Dm * 2;
    u16* projW = (u16*)w;  w += (size_t)Ln * Dm * Dm * 2;
    u16* fc1W = (u16*)w;   w += (size_t)Ln * Dm * DMLP * 2;
    u16* fc2W = (u16*)w;   w += (size_t)Ln * DMLP * Dm * 2;
    float* x  = (float*)w; w += (size_t)Tn * Dm * 4;
    u16* hbuf = (u16*)w;   w += (size_t)Tn * Dm * 2;
    u16* qb   = (u16*)w;   w += (size_t)Tn * Dm * 2;
    u16* kb   = (u16*)w;   w += (size_t)Tn * Dm * 2;
    u16* vb   = (u16*)w;   w += (size_t)Tn * Dm * 2;
    u16* attn = (u16*)w;   w += (size_t)Tn * Dm * 2;
    u16* mlp  = (u16*)w;   w += (size_t)Tn * DMLP * 2;

    // ---- weight prep (bf16 + transpose to [N,K]) ----
    k_cvt<<<(Vn * Dm / 4) / 256, 256, 0, stream>>>(wte, wteB, Vn * Dm / 4);
    dim3 tb(32, 8);
    k_tr<<<dim3(3 * Dm / 32, Dm / 32, Ln), tb, 0, stream>>>(qkvw, qkvW, Dm, 3 * Dm);
    k_tr<<<dim3(Dm / 32, Dm / 32, Ln), tb, 0, stream>>>(projw, projW, Dm, Dm);
    k_tr<<<dim3(DMLP / 32, Dm / 32, Ln), tb, 0, stream>>>(fc1w, fc1W, Dm, DMLP);
    k_tr<<<dim3(Dm / 32, DMLP / 32, Ln), tb, 0, stream>>>(fc2w, fc2W, DMLP, Dm);

    k_embed<<<Tn * Dm / 256, 256, 0, stream>>>(ids, wte, wpe, x);

    for (int l = 0; l < Ln; ++l) {
        k_ln<<<Tn, 256, 0, stream>>>(x, ln1g + l * Dm, ln1b + l * Dm, hbuf, 1e-6f);
        // qkv GEMM with fused repack into q/k/v (q pre-scaled 1/8)
        k_gemm<3><<<dim3(Tn / 128, 3 * Dm / 128), 256, 0, stream>>>(
            hbuf, qkvW + (size_t)l * 3 * Dm * Dm, qkvb + l * 3 * Dm,
            nullptr, nullptr, qb, kb, vb, Tn, 3 * Dm, Dm);
        k_attn<<<Bn * Hn * (Sn / 64), 256, 0, stream>>>(qb, kb, vb, amask, attn);
        // proj: split-K=4, atomic accumulate into x (x already holds residual)
        k_gemm<4><<<dim3(Tn / 128, Dm / 128, 4), 256, 0, stream>>>(
            attn, projW + (size_t)l * Dm * Dm, projb + l * Dm,
            x, nullptr, nullptr, nullptr, nullptr, Tn, Dm, Dm);
        k_ln<<<Tn, 256, 0, stream>>>(x, ln2g + l * Dm, ln2b + l * Dm, hbuf, 1e-6f);
        k_gemm<2><<<dim3(Tn / 128, DMLP / 128), 256, 0, stream>>>(
            hbuf, fc1W + (size_t)l * Dm * DMLP, fc1b + l * DMLP,
            nullptr, mlp, nullptr, nullptr, nullptr, Tn, DMLP, Dm);
        // fc2: split-K=4, atomic accumulate into x
        k_gemm<4><<<dim3(Tn / 128, Dm / 128, 4), 256, 0, stream>>>(
            mlp, fc2W + (size_t)l * DMLP * Dm, fc2b + l * Dm,
            x, nullptr, nullptr, nullptr, nullptr, Tn, Dm, DMLP);
    }

    k_ln<<<Tn, 256, 0, stream>>>(x, lnfg, lnfb, hbuf, 1e-5f);
    // head: pipelined 256x128 kernel, grid = (2048/256) * (50304/128) = 3144
    k_hgemm<<<(Tn / 256) * (Vn / 128), 512, 0, stream>>>(
        hbuf, wteB, headb, (float*)d_out, Tn, Vn, Dm);
}